// Round 7
// baseline (73.397 us; speedup 1.0000x reference)
//
#include <hip/hip_runtime.h>
#include <stdint.h>

// Shapes fixed by setup_inputs(): B=2048, D=1024, H=1024.
#define BB 2048
#define DD 1024
#define HH 1024
#define KK 4096   // D + H + D + H : A' = [x | h_prev | x^2 | h_prev^2]
#define NN 2048   // 2*H : u-gate cols 0..1023, h-gate cols 1024..2047 (r-gate dead)

typedef __bf16 bf16x8 __attribute__((ext_vector_type(8)));
typedef float  f32x4  __attribute__((ext_vector_type(4)));
typedef unsigned short u16x8 __attribute__((ext_vector_type(8)));

__device__ __forceinline__ unsigned short f2bf(float f) {
  union { float f; uint32_t u; } v; v.f = f;
  uint32_t r = (v.u + 0x7FFFu + ((v.u >> 16) & 1u)) >> 16;  // RNE
  return (unsigned short)r;
}
__device__ __forceinline__ float bf2f(unsigned short u) {
  union { float f; uint32_t i; } v; v.i = ((uint32_t)u) << 16; return v.f;
}

__device__ __forceinline__ float softplus_f(float x) {
  return (x > 20.f) ? x : __logf(1.f + __expf(x));
}

// ---------- merged prep: blocks [0,2048) build W'T, blocks [2048,10240) build A' ---
__global__ __launch_bounds__(256) void prep_aw(const float* __restrict__ x,
                                               const float* __restrict__ h,
                                               unsigned short* __restrict__ A,
                                               const float* __restrict__ Wmu,
                                               const float* __restrict__ Wrho,
                                               const float* __restrict__ Umu,
                                               const float* __restrict__ Urho,
                                               const float* __restrict__ ueps,
                                               const float* __restrict__ heps,
                                               unsigned short* __restrict__ Wt) {
  __shared__ float tile[64][65];                // [k][n], 65-pad
  int bxx = blockIdx.x;
  if (bxx >= 2048) {
    // ---- prep_a part ----
    int T = (bxx - 2048) * 256 + threadIdx.x;
    int m  = T >> 10;
    int k4 = (T & 1023) << 2;
    int region = k4 >> 10;                      // 0:x 1:h 2:x^2 3:h^2
    int off = k4 & 1023;
    const float* src = (region & 1) ? h : x;
    float4 v = *(const float4*)(src + (size_t)m * 1024 + off);
    if (region >= 2) { v.x *= v.x; v.y *= v.y; v.z *= v.z; v.w *= v.w; }
    ushort4 o;
    o.x = f2bf(v.x); o.y = f2bf(v.y); o.z = f2bf(v.z); o.w = f2bf(v.w);
    *(ushort4*)(A + (size_t)m * KK + k4) = o;
    return;
  }
  // ---- prep_w part ----
  int bx = bxx;                                 // 32 n-tiles x 64 k-tiles
  int n0 = (bx & 31) * 64;
  int k0 = (bx >> 5) * 64;
  int t = threadIdx.x;

  const float* src; int rowbase; bool sig = (k0 >= 2048);
  if      (k0 < 1024) { src = Wmu;  rowbase = k0; }
  else if (k0 < 2048) { src = Umu;  rowbase = k0 - 1024; }
  else if (k0 < 3072) { src = Wrho; rowbase = k0 - 2048; }
  else                { src = Urho; rowbase = k0 - 3072; }

  int nn  = t & 63;                             // lanes sweep n: coalesced reads
  int kk0 = t >> 6;
  int n   = n0 + nn;
  float eps = 0.f;
  if (sig) eps = (n < 1024) ? ueps[n] : heps[n - 1024];
#pragma unroll
  for (int p = 0; p < 16; ++p) {
    int kk = p * 4 + kk0;
    float v = src[(size_t)(rowbase + kk) * 3072 + 1024 + n];
    if (sig) { float s = softplus_f(v); v = s * s * eps; }
    tile[kk][nn] = v;
  }
  __syncthreads();
  // write phase: each thread emits 2x 16B stores (8 bf16 along k)
#pragma unroll
  for (int p = 0; p < 2; ++p) {
    int idx = p * 256 + t;
    int nw  = idx >> 3;                         // 0..63
    int oc  = idx & 7;                          // k-octet
    u16x8 o8;
#pragma unroll
    for (int e = 0; e < 8; ++e) o8[e] = f2bf(tile[oc * 8 + e][nw]);
    *(u16x8*)&Wt[(size_t)(n0 + nw) * KK + k0 + oc * 8] = o8;
  }
}

// ======== GEMM v4: 256x256 tile, 4 waves, per-wave 128x128, BK=64, 2-buf =========
// Arithmetic intensity 64 FLOP/LDS-byte (vs 42.7 before): per-block LDS read
// drops to 2 MB. Sync: 1 barrier + 1 vmcnt(0) per k-tile; stage(t+1) issued at
// the TOP of iteration t (full-iteration latency lead). Chunk swizzle c^(row&7)
// on global source + read side (gload_lds dest stays linear).
__device__ __forceinline__ void gload16(const unsigned short* g, unsigned short* l) {
  __builtin_amdgcn_global_load_lds((const __attribute__((address_space(1))) void*)g,
                                   (__attribute__((address_space(3))) void*)l, 16, 0, 0);
}

#define BAR() { asm volatile("" ::: "memory"); __builtin_amdgcn_s_barrier(); \
                asm volatile("" ::: "memory"); }
#define VMC(N) { asm volatile("s_waitcnt vmcnt(" #N ")" ::: "memory"); }

template <int SPLITK>
__global__ __launch_bounds__(256, 1) void gemm4w(const unsigned short* __restrict__ A,
                                                 const unsigned short* __restrict__ Bt,
                                                 unsigned short* __restrict__ Gb) {
  constexpr int KSTEPS = (KK / 64) / SPLITK;     // 16 at SPLITK=4
  __shared__ __align__(16) unsigned short lds[65536];   // 128 KiB: 2 bufs x (A32K|B32K)
  const int tid = threadIdx.x;
  const int bx  = blockIdx.x;
  const int tile = bx & 63;                      // 8(M) x 8(N)
  const int kz   = bx >> 6;
  const int m0 = (tile >> 3) * 256;
  const int n0 = (tile & 7) * 256;
  const int kt0 = kz * KSTEPS;
  const int lane = tid & 63;
  const int wid  = tid >> 6;                     // 4 waves: 2x2 grid of 128x128
  const int wr  = wid >> 1;
  const int wc  = wid & 1;
  const int lr  = lane & 15;
  const int lk  = lane >> 4;
  const int swz = lr & 7;

  f32x4 acc[8][8];                               // 256 VGPRs
#pragma unroll
  for (int i = 0; i < 8; ++i)
#pragma unroll
    for (int j = 0; j < 8; ++j) acc[i][j] = (f32x4)0.f;

  // stage k-tile tl: A 2048 chunks + B 2048 chunks, 16 gload16/thread
#define STG(tl) do { if ((tl) < KSTEPS) {                                      \
    unsigned short* lb = &lds[((tl) & 1) * 32768];                             \
    _Pragma("unroll") for (int j = 0; j < 8; ++j) {                            \
      int c = j * 256 + tid; int row = c >> 3; int oc = (c & 7) ^ (row & 7);   \
      gload16(A + (size_t)(m0 + row) * KK + (size_t)(kt0 + (tl)) * 64 + oc * 8,\
              lb + c * 8);                                                     \
    }                                                                          \
    _Pragma("unroll") for (int j = 0; j < 8; ++j) {                            \
      int c = j * 256 + tid; int row = c >> 3; int oc = (c & 7) ^ (row & 7);   \
      gload16(Bt + (size_t)(n0 + row) * KK + (size_t)(kt0 + (tl)) * 64 + oc * 8,\
              lb + 16384 + c * 8);                                             \
    } } } while (0)

  // -------- prologue --------
  STG(0);
  VMC(0); BAR();

#pragma unroll 1
  for (int tc = 0; tc < KSTEPS; ++tc) {
    const unsigned short* lb = &lds[(tc & 1) * 32768];
    STG(tc + 1);                                 // full-iteration latency lead
    bf16x8 b[8][2];
#pragma unroll
    for (int fj = 0; fj < 8; ++fj)
#pragma unroll
      for (int ks = 0; ks < 2; ++ks) {
        int row = wc * 128 + fj * 16 + lr;
        b[fj][ks] = *(const bf16x8*)&lb[16384 + row * 64 + ((ks * 4 + lk) ^ swz) * 8];
      }
#pragma unroll
    for (int q = 0; q < 4; ++q) {
      bf16x8 a2[2][2];
#pragma unroll
      for (int f2 = 0; f2 < 2; ++f2)
#pragma unroll
        for (int ks = 0; ks < 2; ++ks) {
          int row = wr * 128 + q * 32 + f2 * 16 + lr;
          a2[f2][ks] = *(const bf16x8*)&lb[row * 64 + ((ks * 4 + lk) ^ swz) * 8];
        }
      __builtin_amdgcn_s_setprio(1);
#pragma unroll
      for (int ks = 0; ks < 2; ++ks)             // ks outer: 16 indep MFMAs between acc reuse
#pragma unroll
        for (int f2 = 0; f2 < 2; ++f2)
#pragma unroll
          for (int fj = 0; fj < 8; ++fj)
            acc[q * 2 + f2][fj] = __builtin_amdgcn_mfma_f32_16x16x32_bf16(
                a2[f2][ks], b[fj][ks], acc[q * 2 + f2][fj], 0, 0, 0);
      __builtin_amdgcn_s_setprio(0);
    }
    VMC(0); BAR();                               // stage(tc+1) landed; all waves done
  }

  // ---- C repack: f32 acc -> bf16 via per-wave 32 KiB LDS region, swizzled ----
  unsigned short* wl = &lds[wid * 16384];        // 128 rows x 128 cols bf16
#pragma unroll
  for (int fi = 0; fi < 8; ++fi)
#pragma unroll
    for (int fj = 0; fj < 8; ++fj) {
#pragma unroll
      for (int q = 0; q < 4; ++q) {
        int row = fi * 16 + lk * 4 + q;          // 0..127
        int col = fj * 16 + lr;                  // 0..127
        int oc  = (col >> 3) ^ (row & 7);        // bijective within 8-oct half
        wl[row * 128 + oc * 8 + (col & 7)] = f2bf(acc[fi][fj][q]);
      }
    }
  __syncthreads();
  unsigned short* Gz = Gb + (size_t)kz * BB * NN;
#pragma unroll
  for (int i = 0; i < 32; ++i) {
    int idx = i * 64 + lane;
    int r   = idx >> 4;                          // 0..127
    int oc  = idx & 15;
    bf16x8 vv = *(const bf16x8*)&wl[r * 128 + (oc ^ (r & 7)) * 8];
    *(bf16x8*)&Gz[(size_t)(m0 + wr * 128 + r) * NN + n0 + wc * 128 + oc * 8] = vv;
  }
#undef STG
}

// ---------------- epilogue: split-K reduce (bf16 partials) + gates + mix ---------
template <int SPLITK>
__global__ __launch_bounds__(256) void epilogue(const unsigned short* __restrict__ Gb,
                                                const float* __restrict__ hprev,
                                                const float* __restrict__ bmu,
                                                const float* __restrict__ brho,
                                                const float* __restrict__ ueps,
                                                const float* __restrict__ heps,
                                                float* __restrict__ out) {
  int T = blockIdx.x * 256 + threadIdx.x;       // 262144 threads, 8 cols each
  int m  = T >> 7;
  int j8 = (T & 127) << 3;
  float gu[8] = {0.f,0.f,0.f,0.f,0.f,0.f,0.f,0.f};
  float gh[8] = {0.f,0.f,0.f,0.f,0.f,0.f,0.f,0.f};
#pragma unroll
  for (int z = 0; z < SPLITK; ++z) {
    const unsigned short* Gz = Gb + (size_t)z * BB * NN;
    u16x8 a = *(const u16x8*)(Gz + (size_t)m * NN + j8);
    u16x8 c = *(const u16x8*)(Gz + (size_t)m * NN + 1024 + j8);
#pragma unroll
    for (int e = 0; e < 8; ++e) { gu[e] += bf2f(a[e]); gh[e] += bf2f(c[e]); }
  }
  float hp[8], bu[8], ru[8], bh[8], rh[8], ue[8], he[8];
  *(float4*)&hp[0] = *(const float4*)(hprev + (size_t)m * 1024 + j8);
  *(float4*)&hp[4] = *(const float4*)(hprev + (size_t)m * 1024 + j8 + 4);
  *(float4*)&bu[0] = *(const float4*)(bmu + 1024 + j8);
  *(float4*)&bu[4] = *(const float4*)(bmu + 1024 + j8 + 4);
  *(float4*)&ru[0] = *(const float4*)(brho + 1024 + j8);
  *(float4*)&ru[4] = *(const float4*)(brho + 1024 + j8 + 4);
  *(float4*)&bh[0] = *(const float4*)(bmu + 2048 + j8);
  *(float4*)&bh[4] = *(const float4*)(bmu + 2048 + j8 + 4);
  *(float4*)&rh[0] = *(const float4*)(brho + 2048 + j8);
  *(float4*)&rh[4] = *(const float4*)(brho + 2048 + j8 + 4);
  *(float4*)&ue[0] = *(const float4*)(ueps + j8);
  *(float4*)&ue[4] = *(const float4*)(ueps + j8 + 4);
  *(float4*)&he[0] = *(const float4*)(heps + j8);
  *(float4*)&he[4] = *(const float4*)(heps + j8 + 4);
  float o[8];
#pragma unroll
  for (int c = 0; c < 8; ++c) {
    float zu = gu[c] + bu[c] + softplus_f(ru[c]) * ue[c];
    float zh = gh[c] + bh[c] + softplus_f(rh[c]) * he[c];
    float u  = 1.f / (1.f + __expf(-zu));
    float e2 = __expf(2.f * zh);
    float th = 1.f - 2.f / (e2 + 1.f);          // tanh, inf-safe
    o[c] = u * hp[c] + (1.f - u) * th;
  }
  *(float4*)(out + (size_t)m * 1024 + j8)     = *(const float4*)&o[0];
  *(float4*)(out + (size_t)m * 1024 + j8 + 4) = *(const float4*)&o[4];
}

extern "C" void kernel_launch(void* const* d_in, const int* in_sizes, int n_in,
                              void* d_out, int out_size, void* d_ws, size_t ws_size,
                              hipStream_t stream) {
  const float* x     = (const float*)d_in[0];
  const float* hprev = (const float*)d_in[1];
  const float* Wmu   = (const float*)d_in[2];
  const float* Wrho  = (const float*)d_in[3];
  const float* Umu   = (const float*)d_in[4];
  const float* Urho  = (const float*)d_in[5];
  const float* bmu   = (const float*)d_in[6];
  const float* brho  = (const float*)d_in[7];
  const float* ueps  = (const float*)d_in[9];   // d_in[8]=r_eps is dead code
  const float* heps  = (const float*)d_in[10];
  float* out = (float*)d_out;

  size_t aw = (size_t)BB * KK * 2;              // A' bf16, 16 MiB
  size_t ww = (size_t)NN * KK * 2;              // W'T bf16, 16 MiB
  size_t gw = (size_t)BB * NN * 2;              // bf16 partial, 8 MiB each
  unsigned short* Abf = (unsigned short*)d_ws;
  unsigned short* Wt  = (unsigned short*)((char*)d_ws + aw);
  unsigned short* Gb  = (unsigned short*)((char*)d_ws + aw + ww);

  int splitk = 1;
  if      (ws_size >= aw + ww + 4 * gw) splitk = 4;
  else if (ws_size >= aw + ww + 2 * gw) splitk = 2;

  prep_aw<<<10240, 256, 0, stream>>>(x, hprev, Abf, Wmu, Wrho, Umu, Urho,
                                     ueps, heps, Wt);
  if (splitk == 4) {
    gemm4w<4><<<256, 256, 0, stream>>>(Abf, Wt, Gb);
    epilogue<4><<<1024, 256, 0, stream>>>(Gb, hprev, bmu, brho, ueps, heps, out);
  } else if (splitk == 2) {
    gemm4w<2><<<128, 256, 0, stream>>>(Abf, Wt, Gb);
    epilogue<2><<<1024, 256, 0, stream>>>(Gb, hprev, bmu, brho, ueps, heps, out);
  } else {
    gemm4w<1><<<64, 256, 0, stream>>>(Abf, Wt, Gb);
    epilogue<1><<<1024, 256, 0, stream>>>(Gb, hprev, bmu, brho, ueps, heps, out);
  }
}

// Round 8
// 68.383 us; speedup vs baseline: 1.0733x; 1.0733x over previous
//
#include <hip/hip_runtime.h>
#include <stdint.h>

// Shapes fixed by setup_inputs(): B=2048, D=1024, H=1024.
#define BB 2048
#define DD 1024
#define HH 1024
#define KK 4096   // D + H + D + H : A' = [x | h_prev | x^2 | h_prev^2]
#define NN 2048   // 2*H : u-gate cols 0..1023, h-gate cols 1024..2047 (r-gate dead)

typedef __bf16 bf16x8 __attribute__((ext_vector_type(8)));
typedef float  f32x4  __attribute__((ext_vector_type(4)));
typedef unsigned short u16x8 __attribute__((ext_vector_type(8)));

__device__ __forceinline__ unsigned short f2bf(float f) {
  union { float f; uint32_t u; } v; v.f = f;
  uint32_t r = (v.u + 0x7FFFu + ((v.u >> 16) & 1u)) >> 16;  // RNE
  return (unsigned short)r;
}
__device__ __forceinline__ float bf2f(unsigned short u) {
  union { float f; uint32_t i; } v; v.i = ((uint32_t)u) << 16; return v.f;
}

__device__ __forceinline__ float softplus_f(float x) {
  return (x > 20.f) ? x : __logf(1.f + __expf(x));
}

// ---------- merged prep: blocks [0,2048) build W'T, blocks [2048,10240) build A' ---
__global__ __launch_bounds__(256) void prep_aw(const float* __restrict__ x,
                                               const float* __restrict__ h,
                                               unsigned short* __restrict__ A,
                                               const float* __restrict__ Wmu,
                                               const float* __restrict__ Wrho,
                                               const float* __restrict__ Umu,
                                               const float* __restrict__ Urho,
                                               const float* __restrict__ ueps,
                                               const float* __restrict__ heps,
                                               unsigned short* __restrict__ Wt) {
  __shared__ float tile[64][65];                // [k][n], 65-pad
  int bxx = blockIdx.x;
  if (bxx >= 2048) {
    // ---- prep_a part ----
    int T = (bxx - 2048) * 256 + threadIdx.x;
    int m  = T >> 10;
    int k4 = (T & 1023) << 2;
    int region = k4 >> 10;                      // 0:x 1:h 2:x^2 3:h^2
    int off = k4 & 1023;
    const float* src = (region & 1) ? h : x;
    float4 v = *(const float4*)(src + (size_t)m * 1024 + off);
    if (region >= 2) { v.x *= v.x; v.y *= v.y; v.z *= v.z; v.w *= v.w; }
    ushort4 o;
    o.x = f2bf(v.x); o.y = f2bf(v.y); o.z = f2bf(v.z); o.w = f2bf(v.w);
    *(ushort4*)(A + (size_t)m * KK + k4) = o;
    return;
  }
  // ---- prep_w part ----
  int bx = bxx;                                 // 32 n-tiles x 64 k-tiles
  int n0 = (bx & 31) * 64;
  int k0 = (bx >> 5) * 64;
  int t = threadIdx.x;

  const float* src; int rowbase; bool sig = (k0 >= 2048);
  if      (k0 < 1024) { src = Wmu;  rowbase = k0; }
  else if (k0 < 2048) { src = Umu;  rowbase = k0 - 1024; }
  else if (k0 < 3072) { src = Wrho; rowbase = k0 - 2048; }
  else                { src = Urho; rowbase = k0 - 3072; }

  int nn  = t & 63;                             // lanes sweep n: coalesced reads
  int kk0 = t >> 6;
  int n   = n0 + nn;
  float eps = 0.f;
  if (sig) eps = (n < 1024) ? ueps[n] : heps[n - 1024];
#pragma unroll
  for (int p = 0; p < 16; ++p) {
    int kk = p * 4 + kk0;
    float v = src[(size_t)(rowbase + kk) * 3072 + 1024 + n];
    if (sig) { float s = softplus_f(v); v = s * s * eps; }
    tile[kk][nn] = v;
  }
  __syncthreads();
  // write phase: each thread emits 2x 16B stores (8 bf16 along k)
#pragma unroll
  for (int p = 0; p < 2; ++p) {
    int idx = p * 256 + t;
    int nw  = idx >> 3;                         // 0..63
    int oc  = idx & 7;                          // k-octet
    u16x8 o8;
#pragma unroll
    for (int e = 0; e < 8; ++e) o8[e] = f2bf(tile[oc * 8 + e][nw]);
    *(u16x8*)&Wt[(size_t)(n0 + nw) * KK + k0 + oc * 8] = o8;
  }
}

// ================= GEMM: 256x256 tile, BK=64, 8-phase counted-vmcnt ==============
// G_z = A'[:, Kz] @ W'T[:, Kz]^T ; 8 waves (2Mx4N), per-wave 128x64 output.
// XCD-chunked blockIdx swizzle (T1): each XCD gets 32 consecutive work-ids
// (one kz, 4 m-panels x 8 n-panels = 6 MB unique) for L2 panel reuse.
// Pipelined head-reads; bf16 partials repacked via LDS for 16B stores.
__device__ __forceinline__ void gload16(const unsigned short* g, unsigned short* l) {
  __builtin_amdgcn_global_load_lds((const __attribute__((address_space(1))) void*)g,
                                   (__attribute__((address_space(3))) void*)l, 16, 0, 0);
}

#define LOFS(buf, ab, half, row, chunk) \
  ((buf) * 32768 + (ab) * 16384 + (half) * 8192 + (row) * 64 + (chunk) * 8)

#define BAR() { asm volatile("" ::: "memory"); __builtin_amdgcn_s_barrier(); \
                asm volatile("" ::: "memory"); }
#define WAITL() { asm volatile("s_waitcnt lgkmcnt(0)" ::: "memory"); \
                  __builtin_amdgcn_sched_barrier(0); }
#define VMC(N) { asm volatile("s_waitcnt vmcnt(" #N ")" ::: "memory"); }

template <int SPLITK>
__global__ __launch_bounds__(512, 2) void gemm256(const unsigned short* __restrict__ A,
                                                  const unsigned short* __restrict__ Bt,
                                                  unsigned short* __restrict__ Gb) {
  constexpr int KSTEPS = (KK / 64) / SPLITK;     // k-tiles per block (even, >=4)
  __shared__ __align__(16) unsigned short lds[65536];   // 128 KiB
  const int tid = threadIdx.x;
  const int bx  = blockIdx.x;
  // T1: bijective chunked XCD swizzle (nwg is 64/128/256 -> nwg%8==0)
  const int nwg  = SPLITK * 64;
  const int cpx  = nwg >> 3;
  const int wkid = (bx & 7) * cpx + (bx >> 3);
  const int tile = wkid & 63;
  const int kz   = wkid >> 6;
  const int m0 = (tile >> 3) * 256;
  const int n0 = (tile & 7) * 256;
  const int kt0 = kz * KSTEPS;
  const int lane = tid & 63;
  const int wid  = tid >> 6;
  const int wm  = wid >> 2;        // 0..1 : A-half (rows wm*128..+127)
  const int wn  = wid & 3;         // 0..3 : 64-col band
  const int lr  = lane & 15;
  const int lk  = lane >> 4;
  const int swz = lr & 7;
  const int wnh = wn >> 1;         // B-half
  const int wnr = (wn & 1) * 64;   // row base within B-half

  f32x4 acc[8][4];
#pragma unroll
  for (int i = 0; i < 8; ++i)
#pragma unroll
    for (int j = 0; j < 4; ++j) acc[i][j] = (f32x4)0.f;
  bf16x8 b[4][2], aA[2][2], aB[2][2];

#define STAGE(ab, half, tl) do { if ((tl) < KSTEPS) {                          \
    const unsigned short* gb = (ab) ? Bt : A;                                  \
    int p0 = (ab) ? n0 : m0;                                                   \
    unsigned short* ld = &lds[LOFS((tl) & 1, ab, half, 0, 0)];                 \
    _Pragma("unroll") for (int j = 0; j < 2; ++j) {                            \
      int f = j * 512 + tid; int row = f >> 3; int c8 = (f & 7) ^ (row & 7);   \
      gload16(gb + (size_t)(p0 + (half) * 128 + row) * KK                      \
                 + (size_t)(kt0 + (tl)) * 64 + c8 * 8, ld + f * 8);            \
    } } } while (0)

#define READ_B(bufc) do {                                                      \
    _Pragma("unroll") for (int fj = 0; fj < 4; ++fj)                           \
    _Pragma("unroll") for (int ks = 0; ks < 2; ++ks)                           \
      b[fj][ks] = *(const bf16x8*)&lds[LOFS(bufc, 1, wnh, wnr + fj * 16 + lr,  \
                                            (ks * 4 + lk) ^ swz)];             \
  } while (0)

#define READ_AQ(bufc, q, dst) do {                                             \
    _Pragma("unroll") for (int f2 = 0; f2 < 2; ++f2)                           \
    _Pragma("unroll") for (int ks = 0; ks < 2; ++ks)                           \
      dst[f2][ks] = *(const bf16x8*)&lds[LOFS(bufc, 0, wm,                     \
                      (q) * 32 + f2 * 16 + lr, (ks * 4 + lk) ^ swz)];          \
  } while (0)

#define MFMA_Q(q, asrc) do {                                                   \
    __builtin_amdgcn_s_setprio(1);                                             \
    _Pragma("unroll") for (int f2 = 0; f2 < 2; ++f2)                           \
    _Pragma("unroll") for (int fj = 0; fj < 4; ++fj)                           \
    _Pragma("unroll") for (int ks = 0; ks < 2; ++ks)                           \
      acc[(q) * 2 + f2][fj] = __builtin_amdgcn_mfma_f32_16x16x32_bf16(         \
          asrc[f2][ks], b[fj][ks], acc[(q) * 2 + f2][fj], 0, 0, 0);            \
    __builtin_amdgcn_s_setprio(0);                                             \
  } while (0)

  // -------- prologue: tile0 {A0,A1,B0,B1}, tile1 {B0,B1,A0}; drain to tile0 --
  STAGE(0, 0, 0); STAGE(0, 1, 0); STAGE(1, 0, 0); STAGE(1, 1, 0);
  STAGE(1, 0, 1); STAGE(1, 1, 1); STAGE(0, 0, 1);
  VMC(6); BAR();
  READ_B(0); READ_AQ(0, 0, aA);                 // head reads of tile 0

  // -------- main loop: 4 phases per k-tile, head-reads pipelined ------------
#pragma unroll 1
  for (int tc = 0; tc < KSTEPS; ++tc) {
    const int bufc = tc & 1;
    const int nbufc = bufc ^ 1;
    const bool last = (tc + 2 >= KSTEPS);
    // P1: read a q1 ; stage Ah1(tc+1) ; MFMA q0 (operands pre-read in P4/prologue)
    READ_AQ(bufc, 1, aB);
    STAGE(0, 1, tc + 1);
    BAR(); MFMA_Q(0, aA); WAITL(); BAR();
    // P2: read a q2 ; stage Bh0(tc+2) ; MFMA q1
    READ_AQ(bufc, 2, aA);
    STAGE(1, 0, tc + 2);
    BAR(); MFMA_Q(1, aB); WAITL(); BAR();
    // P3: read a q3 ; stage Bh1(tc+2) ; MFMA q2
    READ_AQ(bufc, 3, aB);
    STAGE(1, 1, tc + 2);
    BAR(); MFMA_Q(2, aA); WAITL(); BAR();
    // P4: stage Ah0(tc+2) ; MFMA q3 ; counted vmcnt ; head-read tile tc+1
    STAGE(0, 0, tc + 2);
    BAR(); MFMA_Q(3, aB);
    if (last) { VMC(0); } else { VMC(6); }
    if (tc + 1 < KSTEPS) { READ_B(nbufc); READ_AQ(nbufc, 0, aA); }
    BAR();
  }

  // ---- C repack: f32 acc -> bf16 via per-wave LDS scratch (swizzled), then
  //      16B-contiguous stores. Staging fully drained (VMC(0)+BAR) above.
  unsigned short* wl = &lds[wid * 8192];        // 16 KiB per wave
#pragma unroll
  for (int fi = 0; fi < 8; ++fi)
#pragma unroll
    for (int fj = 0; fj < 4; ++fj) {
      int rowb = fi * 16 + lk * 4;
#pragma unroll
      for (int q = 0; q < 4; ++q) {
        int row  = rowb + q;
        int colw = fj * 16 + lr;
        int el   = (colw & 7) + ((((colw >> 3) ^ row) & 7) << 3);
        wl[row * 64 + el] = f2bf(acc[fi][fj][q]);
      }
    }
  __syncthreads();
  unsigned short* Gz = Gb + (size_t)kz * BB * NN;
  {
    const int rl = lane >> 3;
    const int c  = lane & 7;
#pragma unroll
    for (int i = 0; i < 16; ++i) {
      int r = i * 8 + rl;
      bf16x8 vv = *(const bf16x8*)&wl[r * 64 + (((c ^ r) & 7) << 3)];
      *(bf16x8*)&Gz[(size_t)(m0 + wm * 128 + r) * NN + n0 + wn * 64 + c * 8] = vv;
    }
  }
#undef STAGE
#undef READ_B
#undef READ_AQ
#undef MFMA_Q
}

// ---------------- epilogue: split-K reduce (bf16 partials) + gates + mix ---------
template <int SPLITK>
__global__ __launch_bounds__(256) void epilogue(const unsigned short* __restrict__ Gb,
                                                const float* __restrict__ hprev,
                                                const float* __restrict__ bmu,
                                                const float* __restrict__ brho,
                                                const float* __restrict__ ueps,
                                                const float* __restrict__ heps,
                                                float* __restrict__ out) {
  int T = blockIdx.x * 256 + threadIdx.x;       // 262144 threads, 8 cols each
  int m  = T >> 7;
  int j8 = (T & 127) << 3;
  float gu[8] = {0.f,0.f,0.f,0.f,0.f,0.f,0.f,0.f};
  float gh[8] = {0.f,0.f,0.f,0.f,0.f,0.f,0.f,0.f};
#pragma unroll
  for (int z = 0; z < SPLITK; ++z) {
    const unsigned short* Gz = Gb + (size_t)z * BB * NN;
    u16x8 a = *(const u16x8*)(Gz + (size_t)m * NN + j8);
    u16x8 c = *(const u16x8*)(Gz + (size_t)m * NN + 1024 + j8);
#pragma unroll
    for (int e = 0; e < 8; ++e) { gu[e] += bf2f(a[e]); gh[e] += bf2f(c[e]); }
  }
  float hp[8], bu[8], ru[8], bh[8], rh[8], ue[8], he[8];
  *(float4*)&hp[0] = *(const float4*)(hprev + (size_t)m * 1024 + j8);
  *(float4*)&hp[4] = *(const float4*)(hprev + (size_t)m * 1024 + j8 + 4);
  *(float4*)&bu[0] = *(const float4*)(bmu + 1024 + j8);
  *(float4*)&bu[4] = *(const float4*)(bmu + 1024 + j8 + 4);
  *(float4*)&ru[0] = *(const float4*)(brho + 1024 + j8);
  *(float4*)&ru[4] = *(const float4*)(brho + 1024 + j8 + 4);
  *(float4*)&bh[0] = *(const float4*)(bmu + 2048 + j8);
  *(float4*)&bh[4] = *(const float4*)(bmu + 2048 + j8 + 4);
  *(float4*)&rh[0] = *(const float4*)(brho + 2048 + j8);
  *(float4*)&rh[4] = *(const float4*)(brho + 2048 + j8 + 4);
  *(float4*)&ue[0] = *(const float4*)(ueps + j8);
  *(float4*)&ue[4] = *(const float4*)(ueps + j8 + 4);
  *(float4*)&he[0] = *(const float4*)(heps + j8);
  *(float4*)&he[4] = *(const float4*)(heps + j8 + 4);
  float o[8];
#pragma unroll
  for (int c = 0; c < 8; ++c) {
    float zu = gu[c] + bu[c] + softplus_f(ru[c]) * ue[c];
    float zh = gh[c] + bh[c] + softplus_f(rh[c]) * he[c];
    float u  = 1.f / (1.f + __expf(-zu));
    float e2 = __expf(2.f * zh);
    float th = 1.f - 2.f / (e2 + 1.f);          // tanh, inf-safe
    o[c] = u * hp[c] + (1.f - u) * th;
  }
  *(float4*)(out + (size_t)m * 1024 + j8)     = *(const float4*)&o[0];
  *(float4*)(out + (size_t)m * 1024 + j8 + 4) = *(const float4*)&o[4];
}

extern "C" void kernel_launch(void* const* d_in, const int* in_sizes, int n_in,
                              void* d_out, int out_size, void* d_ws, size_t ws_size,
                              hipStream_t stream) {
  const float* x     = (const float*)d_in[0];
  const float* hprev = (const float*)d_in[1];
  const float* Wmu   = (const float*)d_in[2];
  const float* Wrho  = (const float*)d_in[3];
  const float* Umu   = (const float*)d_in[4];
  const float* Urho  = (const float*)d_in[5];
  const float* bmu   = (const float*)d_in[6];
  const float* brho  = (const float*)d_in[7];
  const float* ueps  = (const float*)d_in[9];   // d_in[8]=r_eps is dead code
  const float* heps  = (const float*)d_in[10];
  float* out = (float*)d_out;

  size_t aw = (size_t)BB * KK * 2;              // A' bf16, 16 MiB
  size_t ww = (size_t)NN * KK * 2;              // W'T bf16, 16 MiB
  size_t gw = (size_t)BB * NN * 2;              // bf16 partial, 8 MiB each
  unsigned short* Abf = (unsigned short*)d_ws;
  unsigned short* Wt  = (unsigned short*)((char*)d_ws + aw);
  unsigned short* Gb  = (unsigned short*)((char*)d_ws + aw + ww);

  int splitk = 1;
  if      (ws_size >= aw + ww + 4 * gw) splitk = 4;
  else if (ws_size >= aw + ww + 2 * gw) splitk = 2;

  prep_aw<<<10240, 256, 0, stream>>>(x, hprev, Abf, Wmu, Wrho, Umu, Urho,
                                     ueps, heps, Wt);
  if (splitk == 4) {
    gemm256<4><<<256, 512, 0, stream>>>(Abf, Wt, Gb);
    epilogue<4><<<1024, 256, 0, stream>>>(Gb, hprev, bmu, brho, ueps, heps, out);
  } else if (splitk == 2) {
    gemm256<2><<<128, 512, 0, stream>>>(Abf, Wt, Gb);
    epilogue<2><<<1024, 256, 0, stream>>>(Gb, hprev, bmu, brho, ueps, heps, out);
  } else {
    gemm256<1><<<64, 512, 0, stream>>>(Abf, Wt, Gb);
    epilogue<1><<<1024, 256, 0, stream>>>(Gb, hprev, bmu, brho, ueps, heps, out);
  }
}

// Round 9
// 65.736 us; speedup vs baseline: 1.1165x; 1.0403x over previous
//
#include <hip/hip_runtime.h>
#include <stdint.h>

// Shapes fixed by setup_inputs(): B=2048, D=1024, H=1024.
#define BB 2048
#define DD 1024
#define HH 1024
#define KK 4096   // D + H + D + H : A' = [x | h_prev | x^2 | h_prev^2]
#define NN 2048   // 2*H : u-gate cols 0..1023, h-gate cols 1024..2047 (r-gate dead)

typedef __bf16 bf16x8 __attribute__((ext_vector_type(8)));
typedef float  f32x4  __attribute__((ext_vector_type(4)));
typedef unsigned short u16x8 __attribute__((ext_vector_type(8)));

__device__ __forceinline__ unsigned short f2bf(float f) {
  union { float f; uint32_t u; } v; v.f = f;
  uint32_t r = (v.u + 0x7FFFu + ((v.u >> 16) & 1u)) >> 16;  // RNE
  return (unsigned short)r;
}
__device__ __forceinline__ float bf2f(unsigned short u) {
  union { float f; uint32_t i; } v; v.i = ((uint32_t)u) << 16; return v.f;
}

__device__ __forceinline__ float softplus_f(float x) {
  return (x > 20.f) ? x : __logf(1.f + __expf(x));
}

// ---------- merged prep: blocks [0,2048) build W'T, blocks [2048,6144) build A' ---
// A'-part dedup: each thread loads ONE float4 from x or h and writes BOTH the
// linear quad (region 0/1) and the squared quad (region 2/3) — halves f32 reads.
__global__ __launch_bounds__(256) void prep_aw(const float* __restrict__ x,
                                               const float* __restrict__ h,
                                               unsigned short* __restrict__ A,
                                               const float* __restrict__ Wmu,
                                               const float* __restrict__ Wrho,
                                               const float* __restrict__ Umu,
                                               const float* __restrict__ Urho,
                                               const float* __restrict__ ueps,
                                               const float* __restrict__ heps,
                                               unsigned short* __restrict__ Wt) {
  __shared__ float tile[64][65];                // [k][n], 65-pad
  int bxx = blockIdx.x;
  if (bxx >= 2048) {
    // ---- prep_a part: 4096 blocks x 256 threads, 1 float4 each ----
    int T = (bxx - 2048) * 256 + threadIdx.x;   // over 2048 x 512 float4 slots
    int m  = T >> 9;                            // row
    int q  = T & 511;                           // float4 index within [x|h] row pair
    int region = q >> 8;                        // 0: x, 1: h
    int off = (q & 255) << 2;                   // element offset in source row
    const float* src = region ? h : x;
    float4 v = *(const float4*)(src + (size_t)m * 1024 + off);
    ushort4 lin, sq;
    lin.x = f2bf(v.x); lin.y = f2bf(v.y); lin.z = f2bf(v.z); lin.w = f2bf(v.w);
    sq.x = f2bf(v.x * v.x); sq.y = f2bf(v.y * v.y);
    sq.z = f2bf(v.z * v.z); sq.w = f2bf(v.w * v.w);
    size_t base = (size_t)m * KK + region * 1024 + off;
    *(ushort4*)(A + base)        = lin;         // region 0/1
    *(ushort4*)(A + base + 2048) = sq;          // region 2/3
    return;
  }
  // ---- prep_w part ----
  int bx = bxx;                                 // 32 n-tiles x 64 k-tiles
  int n0 = (bx & 31) * 64;
  int k0 = (bx >> 5) * 64;
  int t = threadIdx.x;

  const float* src; int rowbase; bool sig = (k0 >= 2048);
  if      (k0 < 1024) { src = Wmu;  rowbase = k0; }
  else if (k0 < 2048) { src = Umu;  rowbase = k0 - 1024; }
  else if (k0 < 3072) { src = Wrho; rowbase = k0 - 2048; }
  else                { src = Urho; rowbase = k0 - 3072; }

  int nn  = t & 63;                             // lanes sweep n: coalesced reads
  int kk0 = t >> 6;
  int n   = n0 + nn;
  float eps = 0.f;
  if (sig) eps = (n < 1024) ? ueps[n] : heps[n - 1024];
#pragma unroll
  for (int p = 0; p < 16; ++p) {
    int kk = p * 4 + kk0;
    float v = src[(size_t)(rowbase + kk) * 3072 + 1024 + n];
    if (sig) { float s = softplus_f(v); v = s * s * eps; }
    tile[kk][nn] = v;
  }
  __syncthreads();
  // write phase: each thread emits 2x 16B stores (8 bf16 along k)
#pragma unroll
  for (int p = 0; p < 2; ++p) {
    int idx = p * 256 + t;
    int nw  = idx >> 3;                         // 0..63
    int oc  = idx & 7;                          // k-octet
    u16x8 o8;
#pragma unroll
    for (int e = 0; e < 8; ++e) o8[e] = f2bf(tile[oc * 8 + e][nw]);
    *(u16x8*)&Wt[(size_t)(n0 + nw) * KK + k0 + oc * 8] = o8;
  }
}

// ================= GEMM: 256x256 tile, BK=64, 8-phase counted-vmcnt ==============
// Frozen R8 structure (verified ledger): G_z = A'[:, Kz] @ W'T[:, Kz]^T.
// 8 waves (2Mx4N), per-wave 128x64; T1 XCD-chunked swizzle; pipelined head-reads;
// bf16 partials repacked via LDS for 16B stores.
__device__ __forceinline__ void gload16(const unsigned short* g, unsigned short* l) {
  __builtin_amdgcn_global_load_lds((const __attribute__((address_space(1))) void*)g,
                                   (__attribute__((address_space(3))) void*)l, 16, 0, 0);
}

#define LOFS(buf, ab, half, row, chunk) \
  ((buf) * 32768 + (ab) * 16384 + (half) * 8192 + (row) * 64 + (chunk) * 8)

#define BAR() { asm volatile("" ::: "memory"); __builtin_amdgcn_s_barrier(); \
                asm volatile("" ::: "memory"); }
#define WAITL() { asm volatile("s_waitcnt lgkmcnt(0)" ::: "memory"); \
                  __builtin_amdgcn_sched_barrier(0); }
#define VMC(N) { asm volatile("s_waitcnt vmcnt(" #N ")" ::: "memory"); }

template <int SPLITK>
__global__ __launch_bounds__(512, 2) void gemm256(const unsigned short* __restrict__ A,
                                                  const unsigned short* __restrict__ Bt,
                                                  unsigned short* __restrict__ Gb) {
  constexpr int KSTEPS = (KK / 64) / SPLITK;     // k-tiles per block (even, >=4)
  __shared__ __align__(16) unsigned short lds[65536];   // 128 KiB
  const int tid = threadIdx.x;
  const int bx  = blockIdx.x;
  // T1: bijective chunked XCD swizzle (nwg is 64/128/256 -> nwg%8==0)
  const int nwg  = SPLITK * 64;
  const int cpx  = nwg >> 3;
  const int wkid = (bx & 7) * cpx + (bx >> 3);
  const int tile = wkid & 63;
  const int kz   = wkid >> 6;
  const int m0 = (tile >> 3) * 256;
  const int n0 = (tile & 7) * 256;
  const int kt0 = kz * KSTEPS;
  const int lane = tid & 63;
  const int wid  = tid >> 6;
  const int wm  = wid >> 2;        // 0..1 : A-half (rows wm*128..+127)
  const int wn  = wid & 3;         // 0..3 : 64-col band
  const int lr  = lane & 15;
  const int lk  = lane >> 4;
  const int swz = lr & 7;
  const int wnh = wn >> 1;         // B-half
  const int wnr = (wn & 1) * 64;   // row base within B-half

  f32x4 acc[8][4];
#pragma unroll
  for (int i = 0; i < 8; ++i)
#pragma unroll
    for (int j = 0; j < 4; ++j) acc[i][j] = (f32x4)0.f;
  bf16x8 b[4][2], aA[2][2], aB[2][2];

#define STAGE(ab, half, tl) do { if ((tl) < KSTEPS) {                          \
    const unsigned short* gb = (ab) ? Bt : A;                                  \
    int p0 = (ab) ? n0 : m0;                                                   \
    unsigned short* ld = &lds[LOFS((tl) & 1, ab, half, 0, 0)];                 \
    _Pragma("unroll") for (int j = 0; j < 2; ++j) {                            \
      int f = j * 512 + tid; int row = f >> 3; int c8 = (f & 7) ^ (row & 7);   \
      gload16(gb + (size_t)(p0 + (half) * 128 + row) * KK                      \
                 + (size_t)(kt0 + (tl)) * 64 + c8 * 8, ld + f * 8);            \
    } } } while (0)

#define READ_B(bufc) do {                                                      \
    _Pragma("unroll") for (int fj = 0; fj < 4; ++fj)                           \
    _Pragma("unroll") for (int ks = 0; ks < 2; ++ks)                           \
      b[fj][ks] = *(const bf16x8*)&lds[LOFS(bufc, 1, wnh, wnr + fj * 16 + lr,  \
                                            (ks * 4 + lk) ^ swz)];             \
  } while (0)

#define READ_AQ(bufc, q, dst) do {                                             \
    _Pragma("unroll") for (int f2 = 0; f2 < 2; ++f2)                           \
    _Pragma("unroll") for (int ks = 0; ks < 2; ++ks)                           \
      dst[f2][ks] = *(const bf16x8*)&lds[LOFS(bufc, 0, wm,                     \
                      (q) * 32 + f2 * 16 + lr, (ks * 4 + lk) ^ swz)];          \
  } while (0)

#define MFMA_Q(q, asrc) do {                                                   \
    __builtin_amdgcn_s_setprio(1);                                             \
    _Pragma("unroll") for (int f2 = 0; f2 < 2; ++f2)                           \
    _Pragma("unroll") for (int fj = 0; fj < 4; ++fj)                           \
    _Pragma("unroll") for (int ks = 0; ks < 2; ++ks)                           \
      acc[(q) * 2 + f2][fj] = __builtin_amdgcn_mfma_f32_16x16x32_bf16(         \
          asrc[f2][ks], b[fj][ks], acc[(q) * 2 + f2][fj], 0, 0, 0);            \
    __builtin_amdgcn_s_setprio(0);                                             \
  } while (0)

  // -------- prologue: tile0 {A0,A1,B0,B1}, tile1 {B0,B1,A0}; VMC(6) retires
  //          exactly tile0's 8 loads (14 issued - 6 left) ----------------------
  STAGE(0, 0, 0); STAGE(0, 1, 0); STAGE(1, 0, 0); STAGE(1, 1, 0);
  STAGE(1, 0, 1); STAGE(1, 1, 1); STAGE(0, 0, 1);
  VMC(6); BAR();
  READ_B(0); READ_AQ(0, 0, aA);                 // head reads of tile 0

  // -------- main loop: 4 phases per k-tile, head-reads pipelined ------------
#pragma unroll 1
  for (int tc = 0; tc < KSTEPS; ++tc) {
    const int bufc = tc & 1;
    const int nbufc = bufc ^ 1;
    const bool last = (tc + 2 >= KSTEPS);
    // P1: read a q1 ; stage Ah1(tc+1) ; MFMA q0 (operands pre-read in P4/prologue)
    READ_AQ(bufc, 1, aB);
    STAGE(0, 1, tc + 1);
    BAR(); MFMA_Q(0, aA); WAITL(); BAR();
    // P2: read a q2 ; stage Bh0(tc+2) ; MFMA q1
    READ_AQ(bufc, 2, aA);
    STAGE(1, 0, tc + 2);
    BAR(); MFMA_Q(1, aB); WAITL(); BAR();
    // P3: read a q3 ; stage Bh1(tc+2) ; MFMA q2
    READ_AQ(bufc, 3, aB);
    STAGE(1, 1, tc + 2);
    BAR(); MFMA_Q(2, aA); WAITL(); BAR();
    // P4: stage Ah0(tc+2) ; MFMA q3 ; counted vmcnt ; head-read tile tc+1
    STAGE(0, 0, tc + 2);
    BAR(); MFMA_Q(3, aB);
    if (last) { VMC(0); } else { VMC(6); }
    if (tc + 1 < KSTEPS) { READ_B(nbufc); READ_AQ(nbufc, 0, aA); }
    BAR();
  }

  // ---- C repack: f32 acc -> bf16 via per-wave LDS scratch (swizzled), then
  //      16B-contiguous stores. Staging fully drained (VMC(0)+BAR) above.
  unsigned short* wl = &lds[wid * 8192];        // 16 KiB per wave
#pragma unroll
  for (int fi = 0; fi < 8; ++fi)
#pragma unroll
    for (int fj = 0; fj < 4; ++fj) {
      int rowb = fi * 16 + lk * 4;
#pragma unroll
      for (int q = 0; q < 4; ++q) {
        int row  = rowb + q;
        int colw = fj * 16 + lr;
        int el   = (colw & 7) + ((((colw >> 3) ^ row) & 7) << 3);
        wl[row * 64 + el] = f2bf(acc[fi][fj][q]);
      }
    }
  __syncthreads();
  unsigned short* Gz = Gb + (size_t)kz * BB * NN;
  {
    const int rl = lane >> 3;
    const int c  = lane & 7;
#pragma unroll
    for (int i = 0; i < 16; ++i) {
      int r = i * 8 + rl;
      bf16x8 vv = *(const bf16x8*)&wl[r * 64 + (((c ^ r) & 7) << 3)];
      *(bf16x8*)&Gz[(size_t)(m0 + wm * 128 + r) * NN + n0 + wn * 64 + c * 8] = vv;
    }
  }
#undef STAGE
#undef READ_B
#undef READ_AQ
#undef MFMA_Q
}

// ---------------- epilogue: split-K reduce (bf16 partials) + gates + mix ---------
template <int SPLITK>
__global__ __launch_bounds__(256) void epilogue(const unsigned short* __restrict__ Gb,
                                                const float* __restrict__ hprev,
                                                const float* __restrict__ bmu,
                                                const float* __restrict__ brho,
                                                const float* __restrict__ ueps,
                                                const float* __restrict__ heps,
                                                float* __restrict__ out) {
  int T = blockIdx.x * 256 + threadIdx.x;       // 262144 threads, 8 cols each
  int m  = T >> 7;
  int j8 = (T & 127) << 3;
  float gu[8] = {0.f,0.f,0.f,0.f,0.f,0.f,0.f,0.f};
  float gh[8] = {0.f,0.f,0.f,0.f,0.f,0.f,0.f,0.f};
#pragma unroll
  for (int z = 0; z < SPLITK; ++z) {
    const unsigned short* Gz = Gb + (size_t)z * BB * NN;
    u16x8 a = *(const u16x8*)(Gz + (size_t)m * NN + j8);
    u16x8 c = *(const u16x8*)(Gz + (size_t)m * NN + 1024 + j8);
#pragma unroll
    for (int e = 0; e < 8; ++e) { gu[e] += bf2f(a[e]); gh[e] += bf2f(c[e]); }
  }
  float hp[8], bu[8], ru[8], bh[8], rh[8], ue[8], he[8];
  *(float4*)&hp[0] = *(const float4*)(hprev + (size_t)m * 1024 + j8);
  *(float4*)&hp[4] = *(const float4*)(hprev + (size_t)m * 1024 + j8 + 4);
  *(float4*)&bu[0] = *(const float4*)(bmu + 1024 + j8);
  *(float4*)&bu[4] = *(const float4*)(bmu + 1024 + j8 + 4);
  *(float4*)&ru[0] = *(const float4*)(brho + 1024 + j8);
  *(float4*)&ru[4] = *(const float4*)(brho + 1024 + j8 + 4);
  *(float4*)&bh[0] = *(const float4*)(bmu + 2048 + j8);
  *(float4*)&bh[4] = *(const float4*)(bmu + 2048 + j8 + 4);
  *(float4*)&rh[0] = *(const float4*)(brho + 2048 + j8);
  *(float4*)&rh[4] = *(const float4*)(brho + 2048 + j8 + 4);
  *(float4*)&ue[0] = *(const float4*)(ueps + j8);
  *(float4*)&ue[4] = *(const float4*)(ueps + j8 + 4);
  *(float4*)&he[0] = *(const float4*)(heps + j8);
  *(float4*)&he[4] = *(const float4*)(heps + j8 + 4);
  float o[8];
#pragma unroll
  for (int c = 0; c < 8; ++c) {
    float zu = gu[c] + bu[c] + softplus_f(ru[c]) * ue[c];
    float zh = gh[c] + bh[c] + softplus_f(rh[c]) * he[c];
    float u  = 1.f / (1.f + __expf(-zu));
    float e2 = __expf(2.f * zh);
    float th = 1.f - 2.f / (e2 + 1.f);          // tanh, inf-safe
    o[c] = u * hp[c] + (1.f - u) * th;
  }
  *(float4*)(out + (size_t)m * 1024 + j8)     = *(const float4*)&o[0];
  *(float4*)(out + (size_t)m * 1024 + j8 + 4) = *(const float4*)&o[4];
}

extern "C" void kernel_launch(void* const* d_in, const int* in_sizes, int n_in,
                              void* d_out, int out_size, void* d_ws, size_t ws_size,
                              hipStream_t stream) {
  const float* x     = (const float*)d_in[0];
  const float* hprev = (const float*)d_in[1];
  const float* Wmu   = (const float*)d_in[2];
  const float* Wrho  = (const float*)d_in[3];
  const float* Umu   = (const float*)d_in[4];
  const float* Urho  = (const float*)d_in[5];
  const float* bmu   = (const float*)d_in[6];
  const float* brho  = (const float*)d_in[7];
  const float* ueps  = (const float*)d_in[9];   // d_in[8]=r_eps is dead code
  const float* heps  = (const float*)d_in[10];
  float* out = (float*)d_out;

  size_t aw = (size_t)BB * KK * 2;              // A' bf16, 16 MiB
  size_t ww = (size_t)NN * KK * 2;              // W'T bf16, 16 MiB
  size_t gw = (size_t)BB * NN * 2;              // bf16 partial, 8 MiB each
  unsigned short* Abf = (unsigned short*)d_ws;
  unsigned short* Wt  = (unsigned short*)((char*)d_ws + aw);
  unsigned short* Gb  = (unsigned short*)((char*)d_ws + aw + ww);

  int splitk = 1;
  if      (ws_size >= aw + ww + 4 * gw) splitk = 4;
  else if (ws_size >= aw + ww + 2 * gw) splitk = 2;

  prep_aw<<<6144, 256, 0, stream>>>(x, hprev, Abf, Wmu, Wrho, Umu, Urho,
                                    ueps, heps, Wt);
  if (splitk == 4) {
    gemm256<4><<<256, 512, 0, stream>>>(Abf, Wt, Gb);
    epilogue<4><<<1024, 256, 0, stream>>>(Gb, hprev, bmu, brho, ueps, heps, out);
  } else if (splitk == 2) {
    gemm256<2><<<128, 512, 0, stream>>>(Abf, Wt, Gb);
    epilogue<2><<<1024, 256, 0, stream>>>(Gb, hprev, bmu, brho, ueps, heps, out);
  } else {
    gemm256<1><<<64, 512, 0, stream>>>(Abf, Wt, Gb);
    epilogue<1><<<1024, 256, 0, stream>>>(Gb, hprev, bmu, brho, ueps, heps, out);
  }
}